// Round 5
// baseline (726.875 us; speedup 1.0000x reference)
//
#include <hip/hip_runtime.h>

#define TPB 256
#define NBMAX 1024     // max coarse buckets (2N/256 = 782 for N=100000)
#define CAP 9216       // per-bucket capacity (mean 8184, sigma ~90 -> +11 sigma)
#define EPB 8192       // edges per block in k_bucket

typedef float f32x4 __attribute__((ext_vector_type(4)));   // native vec for nontemporal builtins
typedef float f32x2 __attribute__((ext_vector_type(2)));

__device__ __forceinline__ float lrelu(float x) { return x > 0.f ? x : 0.2f * x; }

// bf16 helpers (RNE pack)
__device__ __forceinline__ unsigned bfr(float x) {
  unsigned u = __float_as_uint(x);
  return (u + 0x7FFFu + ((u >> 16) & 1u)) >> 16;
}
__device__ __forceinline__ unsigned pk(float a, float b) { return bfr(a) | (bfr(b) << 16); }
__device__ __forceinline__ float ubf(unsigned us) { return __uint_as_float(us << 16); }

// ============================ bucketed CSR build ============================
__global__ void __launch_bounds__(TPB) k_bucket(
    const int* __restrict__ ei, int E, int N, int NB,
    int* __restrict__ cursor, unsigned* __restrict__ items)
{
  __shared__ int hist[NBMAX], base[NBMAX];
  int tid = threadIdx.x;
  for (int i = tid; i < NB; i += TPB) hist[i] = 0;
  __syncthreads();
  int s0 = blockIdx.x * EPB;
  int s1 = min(s0 + EPB, E);
  for (int i = s0 + tid; i < s1; i += TPB) {
    int s = __builtin_nontemporal_load(ei + i);
    int d = __builtin_nontemporal_load(ei + E + i);
    atomicAdd(&hist[d >> 8], 1);
    atomicAdd(&hist[(N + s) >> 8], 1);
  }
  __syncthreads();
  for (int i = tid; i < NB; i += TPB) {
    int c = hist[i];
    base[i] = c ? atomicAdd(&cursor[i], c) : 0;
    hist[i] = 0;
  }
  __syncthreads();
  for (int i = s0 + tid; i < s1; i += TPB) {
    int s = __builtin_nontemporal_load(ei + i);
    int d = __builtin_nontemporal_load(ei + E + i);
    int b1 = d >> 8;
    int p1 = base[b1] + atomicAdd(&hist[b1], 1);
    if (p1 < CAP) items[(size_t)b1 * CAP + p1] = ((unsigned)(d & 255) << 24) | (unsigned)s;
    int k2 = N + s, b2 = k2 >> 8;
    int p2 = base[b2] + atomicAdd(&hist[b2], 1);
    if (p2 < CAP) items[(size_t)b2 * CAP + p2] = ((unsigned)(k2 & 255) << 24) | (unsigned)d;
  }
}

__global__ void __launch_bounds__(TPB) k_csr(
    const int* __restrict__ cursor, unsigned* __restrict__ items,
    int* __restrict__ rowptr, int* __restrict__ rowend, int n2)
{
  __shared__ unsigned stage[CAP];
  __shared__ int cnt_s[TPB], scan_s[TPB], off_s[TPB];
  int tid = threadIdx.x, b = blockIdx.x;
  size_t bbase = (size_t)b * CAP;
  int cnt = min(cursor[b], CAP);
  for (int i = tid; i < cnt; i += TPB) stage[i] = __builtin_nontemporal_load(items + bbase + i);
  cnt_s[tid] = 0;
  __syncthreads();
  for (int i = tid; i < cnt; i += TPB) atomicAdd(&cnt_s[stage[i] >> 24], 1);
  __syncthreads();
  int v = cnt_s[tid];
  scan_s[tid] = v;
  __syncthreads();
#pragma unroll
  for (int o = 1; o < TPB; o <<= 1) {
    int t = (tid >= o) ? scan_s[tid - o] : 0;
    __syncthreads();
    scan_s[tid] += t;
    __syncthreads();
  }
  int excl = scan_s[tid] - v;
  off_s[tid] = excl;
  int g = b * 256 + tid;
  if (g < n2) { rowptr[g] = (int)bbase + excl; rowend[g] = (int)bbase + excl + v; }
  cnt_s[tid] = 0;
  __syncthreads();
  for (int i = tid; i < cnt; i += TPB) {
    unsigned u = stage[i];
    int k = u >> 24;
    int r = atomicAdd(&cnt_s[k], 1);
    items[bbase + off_s[k] + r] = u & 0xFFFFFFu;
  }
}

// ============================ dense node kernels ============================

__global__ void __launch_bounds__(TPB) k_score(
    const float* __restrict__ x1, const float* __restrict__ x2,
    const float* __restrict__ Wq, const float* __restrict__ bq,
    const float* __restrict__ Wk, const float* __restrict__ bk,
    float* __restrict__ escore, float* __restrict__ sumexp, int N)
{
  __shared__ float sWq[128], sWk[160], sbq[16], sbk[16];
  for (int i = threadIdx.x; i < 128; i += TPB) sWq[i] = Wq[i];
  for (int i = threadIdx.x; i < 160; i += TPB) sWk[i] = Wk[i];
  if (threadIdx.x < 16) { sbq[threadIdx.x] = bq[threadIdx.x]; sbk[threadIdx.x] = bk[threadIdx.x]; }
  __syncthreads();
  int n = blockIdx.x * TPB + threadIdx.x;
  float e = 0.f;
  if (n < N) {
    float a[8], b[10];
#pragma unroll
    for (int i = 0; i < 8; i++) a[i] = x1[n*8 + i];
#pragma unroll
    for (int i = 0; i < 10; i++) b[i] = x2[n*10 + i];
    float score = 0.f;
#pragma unroll
    for (int j = 0; j < 16; j++) {
      float q = sbq[j], k = sbk[j];
#pragma unroll
      for (int i = 0; i < 8; i++) q += a[i] * sWq[i*16 + j];
#pragma unroll
      for (int i = 0; i < 10; i++) k += b[i] * sWk[i*16 + j];
      score += q * k;
    }
    e = __expf(score);   // |score| small: exp safe without max-subtraction
    escore[n] = e;
  }
  float v = e;
#pragma unroll
  for (int off = 32; off > 0; off >>= 1) v += __shfl_down(v, off);
  __shared__ float red[TPB / 64];
  if ((threadIdx.x & 63) == 0) red[threadIdx.x >> 6] = v;
  __syncthreads();
  if (threadIdx.x == 0) {
    float s = 0.f;
#pragma unroll
    for (int w = 0; w < TPB / 64; w++) s += red[w];
    atomicAdd(sumexp, s);
  }
}

// fused = (escore/sum)*([x1,x2]@Wv+bv); h1 = fused@W1; pack rec1a/rec1b (bf16) + ed (fp32)
__global__ void __launch_bounds__(TPB) k_A1(
    const float* __restrict__ x1, const float* __restrict__ x2,
    const float* __restrict__ Wv, const float* __restrict__ bv,
    const float* __restrict__ W1, const float* __restrict__ a1s, const float* __restrict__ a1d,
    const float* __restrict__ escore, const float* __restrict__ sumexp,
    unsigned* __restrict__ rec1a, unsigned* __restrict__ rec1b,
    float* __restrict__ ed, int N)
{
  __shared__ float sWv[288], sbv[16], sW1[512], sas[32], sad[32];
  for (int i = threadIdx.x; i < 288; i += TPB) sWv[i] = Wv[i];
  for (int i = threadIdx.x; i < 512; i += TPB) sW1[i] = W1[i];
  if (threadIdx.x < 16) sbv[threadIdx.x] = bv[threadIdx.x];
  if (threadIdx.x < 32) { sas[threadIdx.x] = a1s[threadIdx.x]; sad[threadIdx.x] = a1d[threadIdx.x]; }
  __syncthreads();
  int n = blockIdx.x * TPB + threadIdx.x;
  if (n >= N) return;
  float w = escore[n] / sumexp[0];
  float f[16];
  {
    float a[8], b[10];
#pragma unroll
    for (int i = 0; i < 8; i++) a[i] = x1[n*8 + i];
#pragma unroll
    for (int i = 0; i < 10; i++) b[i] = x2[n*10 + i];
#pragma unroll
    for (int j = 0; j < 16; j++) {
      float v = sbv[j];
#pragma unroll
      for (int i = 0; i < 8; i++) v += a[i] * sWv[i*16 + j];
#pragma unroll
      for (int i = 0; i < 10; i++) v += b[i] * sWv[(8 + i)*16 + j];
      f[j] = w * v;
    }
  }
  float hr[32], esv[8], edv[8];
#pragma unroll
  for (int j = 0; j < 32; j++) {
    float s = 0.f;
#pragma unroll
    for (int i = 0; i < 16; i++) s += f[i] * sW1[i*32 + j];
    hr[j] = s;
  }
#pragma unroll
  for (int hh = 0; hh < 8; hh++) {
    float s = 0.f, d = 0.f;
#pragma unroll
    for (int c = 0; c < 4; c++) { s += hr[hh*4+c]*sas[hh*4+c]; d += hr[hh*4+c]*sad[hh*4+c]; }
    esv[hh] = s; edv[hh] = d;
  }
  // rec layout (10 uints): [0..1]=es bf16 x4, [2+2h,3+2h]=h[h][0..3] bf16
  unsigned* ra = rec1a + (size_t)n*10;
  unsigned* rb = rec1b + (size_t)n*10;
  ra[0] = pk(esv[0], esv[1]); ra[1] = pk(esv[2], esv[3]);
  rb[0] = pk(esv[4], esv[5]); rb[1] = pk(esv[6], esv[7]);
#pragma unroll
  for (int hh = 0; hh < 4; hh++) {
    ra[2+2*hh] = pk(hr[hh*4+0], hr[hh*4+1]);
    ra[3+2*hh] = pk(hr[hh*4+2], hr[hh*4+3]);
    rb[2+2*hh] = pk(hr[16+hh*4+0], hr[16+hh*4+1]);
    rb[3+2*hh] = pk(hr[16+hh*4+2], hr[16+hh*4+3]);
  }
  f32x4 e0 = {edv[0], edv[1], edv[2], edv[3]};
  f32x4 e1 = {edv[4], edv[5], edv[6], edv[7]};
  *(f32x4*)(ed + n*8)     = e0;
  *(f32x4*)(ed + n*8 + 4) = e1;
}

// X(32)@W2 -> rec2 (bf16) + ed[0..3]
__global__ void __launch_bounds__(TPB) k_B2(
    const float* __restrict__ W2, const float* __restrict__ a2s, const float* __restrict__ a2d,
    const float* __restrict__ X,
    unsigned* __restrict__ rec2, float* __restrict__ ed, int N)
{
  __shared__ float sW[512], sas[16], sad[16];
  for (int i = threadIdx.x; i < 512; i += TPB) sW[i] = W2[i];
  if (threadIdx.x < 16) { sas[threadIdx.x] = a2s[threadIdx.x]; sad[threadIdx.x] = a2d[threadIdx.x]; }
  __syncthreads();
  int n = blockIdx.x * TPB + threadIdx.x;
  if (n >= N) return;
  float Xr[32];
#pragma unroll
  for (int i = 0; i < 8; i++) {
    f32x4 t = __builtin_nontemporal_load((const f32x4*)(X + n*32) + i);
    Xr[i*4+0] = t.x; Xr[i*4+1] = t.y; Xr[i*4+2] = t.z; Xr[i*4+3] = t.w;
  }
  float hr[16];
#pragma unroll
  for (int j = 0; j < 16; j++) {
    float s = 0.f;
#pragma unroll
    for (int f = 0; f < 32; f++) s += Xr[f] * sW[f*16 + j];
    hr[j] = s;
  }
  float esv[4], edv[4];
#pragma unroll
  for (int hh = 0; hh < 4; hh++) {
    float s = 0.f, d = 0.f;
#pragma unroll
    for (int c = 0; c < 4; c++) { s += hr[hh*4+c]*sas[hh*4+c]; d += hr[hh*4+c]*sad[hh*4+c]; }
    esv[hh] = s; edv[hh] = d;
  }
  unsigned* r = rec2 + (size_t)n*10;
  r[0] = pk(esv[0], esv[1]); r[1] = pk(esv[2], esv[3]);
#pragma unroll
  for (int hh = 0; hh < 4; hh++) {
    r[2+2*hh] = pk(hr[hh*4+0], hr[hh*4+1]);
    r[3+2*hh] = pk(hr[hh*4+2], hr[hh*4+3]);
  }
  f32x4 e0 = {edv[0], edv[1], edv[2], edv[3]};
  *(f32x4*)(ed + n*8) = e0;
}

// X3(16)@W3 -> rec3 (fp32: [es0,es1,h0..h7]) + ed[0..1]
__global__ void __launch_bounds__(TPB) k_B3(
    const float* __restrict__ W3, const float* __restrict__ a3s, const float* __restrict__ a3d,
    const float* __restrict__ X3,
    float* __restrict__ rec3, float* __restrict__ ed, int N)
{
  __shared__ float sW[128], sas[8], sad[8];
  for (int i = threadIdx.x; i < 128; i += TPB) sW[i] = W3[i];
  if (threadIdx.x < 8) { sas[threadIdx.x] = a3s[threadIdx.x]; sad[threadIdx.x] = a3d[threadIdx.x]; }
  __syncthreads();
  int n = blockIdx.x * TPB + threadIdx.x;
  if (n >= N) return;
  float Xr[16];
#pragma unroll
  for (int i = 0; i < 4; i++) {
    f32x4 t = __builtin_nontemporal_load((const f32x4*)(X3 + n*16) + i);
    Xr[i*4+0] = t.x; Xr[i*4+1] = t.y; Xr[i*4+2] = t.z; Xr[i*4+3] = t.w;
  }
  float hr[8];
#pragma unroll
  for (int j = 0; j < 8; j++) {
    float s = 0.f;
#pragma unroll
    for (int f = 0; f < 16; f++) s += Xr[f] * sW[f*8 + j];
    hr[j] = s;
  }
  float* r = rec3 + (size_t)n*10;
#pragma unroll
  for (int hh = 0; hh < 2; hh++) {
    float s = 0.f, d = 0.f;
#pragma unroll
    for (int c = 0; c < 4; c++) { s += hr[hh*4+c]*sas[hh*4+c]; d += hr[hh*4+c]*sad[hh*4+c]; }
    r[hh] = s;
    ed[n*8 + hh] = d;
  }
#pragma unroll
  for (int hh = 0; hh < 2; hh++) {
    f32x2 a = {hr[hh*4+0], hr[hh*4+1]};
    f32x2 b = {hr[hh*4+2], hr[hh*4+3]};
    *(f32x2*)(r + 2 + hh*4)     = a;
    *(f32x2*)(r + 2 + hh*4 + 2) = b;
  }
}

// ==================== gather passes (L2-resident records) ===================
// Layer 1, half-head pass P (heads P*4..P*4+3). 4 threads per dst.
template<int P>
__global__ void __launch_bounds__(TPB) k_gat1(
    const int* __restrict__ rowptr, const int* __restrict__ rowend, const int* __restrict__ col,
    const unsigned* __restrict__ rec, const float* __restrict__ ed,
    const float* __restrict__ b1, float* __restrict__ X, int N)
{
  int t = blockIdx.x * TPB + threadIdx.x;
  if (t >= N * 4) return;
  int d = t >> 2, hp = t & 3;
  float edv = ed[d*8 + P*4 + hp];
  f32x4 acc = {0.f, 0.f, 0.f, 0.f};
  float z = 0.f;
  { // self-loop
    const unsigned* rp = rec + (size_t)d*10;
    float esv = ubf((rp[hp >> 1] >> ((hp & 1) * 16)) & 0xFFFFu);
    uint2 hv = *(const uint2*)(rp + 2 + 2*hp);
    float w = __expf(lrelu(esv + edv));
    z += w;
    acc.x += w * ubf(hv.x & 0xFFFFu); acc.y += w * ubf(hv.x >> 16);
    acc.z += w * ubf(hv.y & 0xFFFFu); acc.w += w * ubf(hv.y >> 16);
  }
  int e0 = rowptr[d], e1 = rowend[d];
  for (int e = e0; e < e1; e++) {
    int s = __builtin_nontemporal_load(col + e);
    const unsigned* rp = rec + (size_t)s*10;
    float esv = ubf((rp[hp >> 1] >> ((hp & 1) * 16)) & 0xFFFFu);
    uint2 hv = *(const uint2*)(rp + 2 + 2*hp);
    float w = __expf(lrelu(esv + edv));
    z += w;
    acc.x += w * ubf(hv.x & 0xFFFFu); acc.y += w * ubf(hv.x >> 16);
    acc.z += w * ubf(hv.y & 0xFFFFu); acc.w += w * ubf(hv.y >> 16);
  }
  float inv = 1.f / z;
  const f32x4 bb = *(const f32x4*)(b1 + (P*4 + hp)*4);
  f32x4 o = { acc.x*inv + bb.x, acc.y*inv + bb.y, acc.z*inv + bb.z, acc.w*inv + bb.w };
  __builtin_nontemporal_store(o, (f32x4*)(X + d*32 + (P*4 + hp)*4));
}

// Layer 2 (H=4), bf16 rec2 -> X3 (stride 16)
__global__ void __launch_bounds__(TPB) k_gat2(
    const int* __restrict__ rowptr, const int* __restrict__ rowend, const int* __restrict__ col,
    const unsigned* __restrict__ rec, const float* __restrict__ ed,
    const float* __restrict__ b2, float* __restrict__ X3, int N)
{
  int t = blockIdx.x * TPB + threadIdx.x;
  if (t >= N * 4) return;
  int d = t >> 2, hh = t & 3;
  float edv = ed[d*8 + hh];
  f32x4 acc = {0.f, 0.f, 0.f, 0.f};
  float z = 0.f;
  {
    const unsigned* rp = rec + (size_t)d*10;
    float esv = ubf((rp[hh >> 1] >> ((hh & 1) * 16)) & 0xFFFFu);
    uint2 hv = *(const uint2*)(rp + 2 + 2*hh);
    float w = __expf(lrelu(esv + edv));
    z += w;
    acc.x += w * ubf(hv.x & 0xFFFFu); acc.y += w * ubf(hv.x >> 16);
    acc.z += w * ubf(hv.y & 0xFFFFu); acc.w += w * ubf(hv.y >> 16);
  }
  int e0 = rowptr[d], e1 = rowend[d];
  for (int e = e0; e < e1; e++) {
    int s = __builtin_nontemporal_load(col + e);
    const unsigned* rp = rec + (size_t)s*10;
    float esv = ubf((rp[hh >> 1] >> ((hh & 1) * 16)) & 0xFFFFu);
    uint2 hv = *(const uint2*)(rp + 2 + 2*hh);
    float w = __expf(lrelu(esv + edv));
    z += w;
    acc.x += w * ubf(hv.x & 0xFFFFu); acc.y += w * ubf(hv.x >> 16);
    acc.z += w * ubf(hv.y & 0xFFFFu); acc.w += w * ubf(hv.y >> 16);
  }
  float inv = 1.f / z;
  const f32x4 bb = *(const f32x4*)(b2 + hh*4);
  f32x4 o = { acc.x*inv + bb.x, acc.y*inv + bb.y, acc.z*inv + bb.z, acc.w*inv + bb.w };
  __builtin_nontemporal_store(o, (f32x4*)(X3 + d*16 + hh*4));
}

// Layer 3 (H=2), fp32 rec3 -> x4 (stride 8)
__global__ void __launch_bounds__(TPB) k_gat3(
    const int* __restrict__ rowptr, const int* __restrict__ rowend, const int* __restrict__ col,
    const float* __restrict__ rec, const float* __restrict__ ed,
    const float* __restrict__ b3, float* __restrict__ x4, int N)
{
  int t = blockIdx.x * TPB + threadIdx.x;
  if (t >= N * 2) return;
  int d = t >> 1, hh = t & 1;
  float edv = ed[d*8 + hh];
  f32x4 acc = {0.f, 0.f, 0.f, 0.f};
  float z = 0.f;
  {
    const float* rp = rec + (size_t)d*10;
    float esv = rp[hh];
    f32x2 a = *(const f32x2*)(rp + 2 + hh*4);
    f32x2 b = *(const f32x2*)(rp + 2 + hh*4 + 2);
    float w = __expf(lrelu(esv + edv));
    z += w; acc.x += w*a.x; acc.y += w*a.y; acc.z += w*b.x; acc.w += w*b.y;
  }
  int e0 = rowptr[d], e1 = rowend[d];
  for (int e = e0; e < e1; e++) {
    int s = __builtin_nontemporal_load(col + e);
    const float* rp = rec + (size_t)s*10;
    float esv = rp[hh];
    f32x2 a = *(const f32x2*)(rp + 2 + hh*4);
    f32x2 b = *(const f32x2*)(rp + 2 + hh*4 + 2);
    float w = __expf(lrelu(esv + edv));
    z += w; acc.x += w*a.x; acc.y += w*a.y; acc.z += w*b.x; acc.w += w*b.y;
  }
  float inv = 1.f / z;
  const f32x4 bb = *(const f32x4*)(b3 + hh*4);
  f32x4 o = { acc.x*inv + bb.x, acc.y*inv + bb.y, acc.z*inv + bb.z, acc.w*inv + bb.w };
  __builtin_nontemporal_store(o, (f32x4*)(x4 + d*8 + hh*4));
}

// ============================ adjacency + final =============================
__global__ void __launch_bounds__(TPB) k_adj_final(
    const int* __restrict__ rowptr, const int* __restrict__ rowend, const int* __restrict__ col,
    const float* __restrict__ x4, const float* __restrict__ Wl2,
    float* __restrict__ out, int N)
{
  __shared__ float sW[8];
  if (threadIdx.x < 8) sW[threadIdx.x] = Wl2[threadIdx.x];
  __syncthreads();
  int t = blockIdx.x * TPB + threadIdx.x;
  if (t >= N * 2) return;
  int r = t >> 1, q = t & 1;
  int e0 = rowptr[N + r], e1 = rowend[N + r];
  f32x4 acc = {0.f, 0.f, 0.f, 0.f};
  for (int e = e0; e < e1; e++) {
    int c = __builtin_nontemporal_load(col + e);
    f32x4 xv = *(const f32x4*)(x4 + c*8 + q*4);
    acc.x += xv.x; acc.y += xv.y; acc.z += xv.z; acc.w += xv.w;
  }
  int deg = e1 - e0;
  float inv = deg > 0 ? 1.f / (float)deg : 0.f;
  f32x4 R = { acc.x*inv, acc.y*inv, acc.z*inv, acc.w*inv };
  f32x4 xo = *(const f32x4*)(x4 + r*8 + q*4);
  float part = xo.x*R.x + xo.y*R.y + xo.z*R.z + xo.w*R.w
             + R.x*sW[q*4+0] + R.y*sW[q*4+1] + R.z*sW[q*4+2] + R.w*sW[q*4+3];
  part += __shfl_xor(part, 1);
  if (q == 0) out[r] = part;
}

// ============================ launch ========================================
extern "C" void kernel_launch(void* const* d_in, const int* in_sizes, int n_in,
                              void* d_out, int out_size, void* d_ws, size_t ws_size,
                              hipStream_t stream)
{
  const float* x1  = (const float*)d_in[0];
  const float* x2  = (const float*)d_in[1];
  const int*   ei  = (const int*)d_in[2];
  const float* Wq  = (const float*)d_in[4];
  const float* bq  = (const float*)d_in[5];
  const float* Wk  = (const float*)d_in[6];
  const float* bk  = (const float*)d_in[7];
  const float* Wv  = (const float*)d_in[8];
  const float* bv  = (const float*)d_in[9];
  const float* W1  = (const float*)d_in[10];
  const float* a1s = (const float*)d_in[11];
  const float* a1d = (const float*)d_in[12];
  const float* b1  = (const float*)d_in[13];
  const float* W2  = (const float*)d_in[14];
  const float* a2s = (const float*)d_in[15];
  const float* a2d = (const float*)d_in[16];
  const float* b2  = (const float*)d_in[17];
  const float* W3  = (const float*)d_in[18];
  const float* a3s = (const float*)d_in[19];
  const float* a3d = (const float*)d_in[20];
  const float* b3  = (const float*)d_in[21];
  const float* Wl2 = (const float*)d_in[22];

  int N = in_sizes[0] / 8;
  int E = in_sizes[2] / 2;
  int n2 = 2 * N;
  int NB = (n2 + 255) >> 8;

  // ---- workspace (element offsets all multiples of 4 -> 16B aligned) ----
  int* cursor   = (int*)d_ws;                           // 1024 (zeroed)
  float* sumexp = (float*)(cursor + 1024);              // 16 (1 used, zeroed)
  int* rowptr   = (int*)(sumexp + 16);                  // 2N
  int* rowend   = rowptr + (size_t)n2;                  // 2N
  unsigned* items = (unsigned*)(rowend + (size_t)n2);   // NB*CAP (-> col in place)
  unsigned* rec1a = items + (size_t)NB * CAP;           // 10N (4.0 MB, L2-resident)
  unsigned* rec1b = rec1a + 10ull*N;                    // 10N (later aliased by x4)
  unsigned* rec2  = rec1b + 10ull*N;                    // 10N
  float* rec3     = (float*)(rec2 + 10ull*N);           // 10N
  float* ed       = rec3 + 10ull*N;                     // 8N
  float* escore   = ed + 8ull*N;                        // N
  float* X        = escore + (size_t)N;                 // 32N (X3 aliases, stride 16)
  float* X3 = X;
  float* x4 = (float*)rec1b;                            // 8N (rec1b dead by then)
  // total ~62.8 MB

  int gN = (N + TPB - 1) / TPB;
  int gB = (E + EPB - 1) / EPB;
  int g4 = (N*4 + TPB - 1) / TPB;
  int g2 = (N*2 + TPB - 1) / TPB;

  (void)hipMemsetAsync(d_ws, 0, (1024 + 16) * sizeof(int), stream);  // cursor + sumexp

  // CSR build
  k_bucket<<<gB, TPB, 0, stream>>>(ei, E, N, NB, cursor, items);
  k_csr<<<NB, TPB, 0, stream>>>(cursor, items, rowptr, rowend, n2);
  int* colv = (int*)items;

  // dense prologue
  k_score<<<gN, TPB, 0, stream>>>(x1, x2, Wq, bq, Wk, bk, escore, sumexp, N);
  k_A1<<<gN, TPB, 0, stream>>>(x1, x2, Wv, bv, W1, a1s, a1d, escore, sumexp, rec1a, rec1b, ed, N);

  // GAT layer 1 (two 4-head passes, 4 MB record each)
  k_gat1<0><<<g4, TPB, 0, stream>>>(rowptr, rowend, colv, rec1a, ed, b1, X, N);
  k_gat1<1><<<g4, TPB, 0, stream>>>(rowptr, rowend, colv, rec1b, ed, b1, X, N);
  // GAT layer 2
  k_B2<<<gN, TPB, 0, stream>>>(W2, a2s, a2d, X, rec2, ed, N);
  k_gat2<<<g4, TPB, 0, stream>>>(rowptr, rowend, colv, rec2, ed, b2, X3, N);
  // GAT layer 3
  k_B3<<<gN, TPB, 0, stream>>>(W3, a3s, a3d, X3, rec3, ed, N);
  k_gat3<<<g2, TPB, 0, stream>>>(rowptr, rowend, colv, rec3, ed, b3, x4, N);

  // adjacency readout
  k_adj_final<<<g2, TPB, 0, stream>>>(rowptr, rowend, colv, x4, Wl2, (float*)d_out, N);
}

// Round 6
// 565.692 us; speedup vs baseline: 1.2849x; 1.2849x over previous
//
#include <hip/hip_runtime.h>

#define TPB 256
#define NBMAX 1024     // max coarse buckets (2N/256 = 782 for N=100000)
#define CAP 9216       // per-bucket capacity (mean 8184, sigma ~90 -> +11 sigma)
#define EPB 4096       // edges per block in k_bucket (16/thread)

typedef float f32x4 __attribute__((ext_vector_type(4)));
typedef float f32x2 __attribute__((ext_vector_type(2)));

__device__ __forceinline__ float lrelu(float x) { return x > 0.f ? x : 0.2f * x; }

// bf16 helpers (RNE pack)
__device__ __forceinline__ unsigned bfr(float x) {
  unsigned u = __float_as_uint(x);
  return (u + 0x7FFFu + ((u >> 16) & 1u)) >> 16;
}
__device__ __forceinline__ unsigned pk(float a, float b) { return bfr(a) | (bfr(b) << 16); }
__device__ __forceinline__ float ubf(unsigned us) { return __uint_as_float(us << 16); }

// ============================ bucketed CSR build ============================
// Pass 1: per-block LDS histogram + scan + LDS bucket-major staging, then
// ordered (coalesced) write-out into padded global buckets.
__global__ void __launch_bounds__(TPB) k_bucket(
    const int* __restrict__ ei, int E, int N,
    int* __restrict__ cursor, unsigned* __restrict__ items)
{
  __shared__ int hist[NBMAX];        // counts -> rank counters
  __shared__ int lofs[NBMAX + 1];    // exclusive scan (stage offsets)
  __shared__ int basem[NBMAX];       // b*CAP + resv - lofs[b]
  __shared__ int scan_s[TPB];
  __shared__ unsigned stage[2 * EPB];
  int tid = threadIdx.x;
  for (int i = tid; i < NBMAX; i += TPB) hist[i] = 0;
  int s0 = blockIdx.x * EPB;
  int nE = min(EPB, E - s0);
  int sv[EPB / TPB], dv[EPB / TPB];
  __syncthreads();
#pragma unroll
  for (int k = 0; k < EPB / TPB; k++) {
    int li = tid + k * TPB;
    if (li < nE) {
      int i = s0 + li;
      sv[k] = __builtin_nontemporal_load(ei + i);
      dv[k] = __builtin_nontemporal_load(ei + E + i);
      atomicAdd(&hist[dv[k] >> 8], 1);
      atomicAdd(&hist[(N + sv[k]) >> 8], 1);
    }
  }
  __syncthreads();
  // 1024-bin exclusive scan; thread t owns bins 4t..4t+3
  int b0 = tid * 4;
  int c0 = hist[b0], c1 = hist[b0 + 1], c2 = hist[b0 + 2], c3 = hist[b0 + 3];
  int tsum = c0 + c1 + c2 + c3;
  scan_s[tid] = tsum;
  __syncthreads();
#pragma unroll
  for (int o = 1; o < TPB; o <<= 1) {
    int t = (tid >= o) ? scan_s[tid - o] : 0;
    __syncthreads();
    scan_s[tid] += t;
    __syncthreads();
  }
  int run = scan_s[tid] - tsum;
  int cs[4] = {c0, c1, c2, c3};
#pragma unroll
  for (int j = 0; j < 4; j++) {
    int b = b0 + j, c = cs[j];
    lofs[b] = run;
    int resv = c ? atomicAdd(&cursor[b], c) : 0;
    basem[b] = b * CAP + resv - run;
    hist[b] = 0;                     // rank counters for phase 3
    run += c;
  }
  if (tid == TPB - 1) lofs[NBMAX] = run;
  __syncthreads();
  // phase 3: rank-scatter into LDS stage (bucket-major)
#pragma unroll
  for (int k = 0; k < EPB / TPB; k++) {
    int li = tid + k * TPB;
    if (li < nE) {
      int s = sv[k], d = dv[k];
      int b1 = d >> 8;
      int p1 = lofs[b1] + atomicAdd(&hist[b1], 1);
      stage[p1] = ((unsigned)(d & 255) << 24) | (unsigned)s;
      int k2 = N + s, b2 = k2 >> 8;
      int p2 = lofs[b2] + atomicAdd(&hist[b2], 1);
      stage[p2] = ((unsigned)(k2 & 255) << 24) | (unsigned)d;
    }
  }
  __syncthreads();
  // phase 4: ordered write-out (consecutive idx -> consecutive dest per bucket)
  int total = 2 * nE;
  for (int idx = tid; idx < total; idx += TPB) {
    unsigned u = stage[idx];
    int lo = 0, hi = NBMAX;          // largest b with lofs[b] <= idx
    while (hi - lo > 1) { int mid = (lo + hi) >> 1; if (lofs[mid] <= idx) lo = mid; else hi = mid; }
    int dest = basem[lo] + idx;
    if (dest < (lo + 1) * CAP) items[dest] = u;
  }
}

// Pass 2: one block per bucket — LDS stage, 256-bin count+scan, in-place scatter
__global__ void __launch_bounds__(TPB) k_csr(
    const int* __restrict__ cursor, unsigned* __restrict__ items,
    int* __restrict__ rowptr, int* __restrict__ rowend, int n2)
{
  __shared__ unsigned stage[CAP];
  __shared__ int cnt_s[TPB], scan_s[TPB], off_s[TPB];
  int tid = threadIdx.x, b = blockIdx.x;
  size_t bbase = (size_t)b * CAP;
  int cnt = min(cursor[b], CAP);
  for (int i = tid; i < cnt; i += TPB) stage[i] = __builtin_nontemporal_load(items + bbase + i);
  cnt_s[tid] = 0;
  __syncthreads();
  for (int i = tid; i < cnt; i += TPB) atomicAdd(&cnt_s[stage[i] >> 24], 1);
  __syncthreads();
  int v = cnt_s[tid];
  scan_s[tid] = v;
  __syncthreads();
#pragma unroll
  for (int o = 1; o < TPB; o <<= 1) {
    int t = (tid >= o) ? scan_s[tid - o] : 0;
    __syncthreads();
    scan_s[tid] += t;
    __syncthreads();
  }
  int excl = scan_s[tid] - v;
  off_s[tid] = excl;
  int g = b * 256 + tid;
  if (g < n2) { rowptr[g] = (int)bbase + excl; rowend[g] = (int)bbase + excl + v; }
  cnt_s[tid] = 0;
  __syncthreads();
  for (int i = tid; i < cnt; i += TPB) {
    unsigned u = stage[i];
    int k = u >> 24;
    int r = atomicAdd(&cnt_s[k], 1);
    items[bbase + off_s[k] + r] = u & 0xFFFFFFu;
  }
}

// ============================ dense node kernels ============================

__global__ void __launch_bounds__(TPB) k_score(
    const float* __restrict__ x1, const float* __restrict__ x2,
    const float* __restrict__ Wq, const float* __restrict__ bq,
    const float* __restrict__ Wk, const float* __restrict__ bk,
    float* __restrict__ escore, float* __restrict__ sumexp, int N)
{
  __shared__ float sWq[128], sWk[160], sbq[16], sbk[16];
  for (int i = threadIdx.x; i < 128; i += TPB) sWq[i] = Wq[i];
  for (int i = threadIdx.x; i < 160; i += TPB) sWk[i] = Wk[i];
  if (threadIdx.x < 16) { sbq[threadIdx.x] = bq[threadIdx.x]; sbk[threadIdx.x] = bk[threadIdx.x]; }
  __syncthreads();
  int n = blockIdx.x * TPB + threadIdx.x;
  float e = 0.f;
  if (n < N) {
    float a[8], b[10];
#pragma unroll
    for (int i = 0; i < 8; i++) a[i] = x1[n*8 + i];
#pragma unroll
    for (int i = 0; i < 10; i++) b[i] = x2[n*10 + i];
    float score = 0.f;
#pragma unroll
    for (int j = 0; j < 16; j++) {
      float q = sbq[j], k = sbk[j];
#pragma unroll
      for (int i = 0; i < 8; i++) q += a[i] * sWq[i*16 + j];
#pragma unroll
      for (int i = 0; i < 10; i++) k += b[i] * sWk[i*16 + j];
      score += q * k;
    }
    e = __expf(score);   // |score| small: exp safe without max-subtraction
    escore[n] = e;
  }
  float v = e;
#pragma unroll
  for (int off = 32; off > 0; off >>= 1) v += __shfl_down(v, off);
  __shared__ float red[TPB / 64];
  if ((threadIdx.x & 63) == 0) red[threadIdx.x >> 6] = v;
  __syncthreads();
  if (threadIdx.x == 0) {
    float s = 0.f;
#pragma unroll
    for (int w = 0; w < TPB / 64; w++) s += red[w];
    atomicAdd(sumexp, s);
  }
}

__global__ void __launch_bounds__(TPB) k_A1(
    const float* __restrict__ x1, const float* __restrict__ x2,
    const float* __restrict__ Wv, const float* __restrict__ bv,
    const float* __restrict__ W1, const float* __restrict__ a1s, const float* __restrict__ a1d,
    const float* __restrict__ escore, const float* __restrict__ sumexp,
    unsigned* __restrict__ rec1a, unsigned* __restrict__ rec1b,
    float* __restrict__ ed, int N)
{
  __shared__ float sWv[288], sbv[16], sW1[512], sas[32], sad[32];
  for (int i = threadIdx.x; i < 288; i += TPB) sWv[i] = Wv[i];
  for (int i = threadIdx.x; i < 512; i += TPB) sW1[i] = W1[i];
  if (threadIdx.x < 16) sbv[threadIdx.x] = bv[threadIdx.x];
  if (threadIdx.x < 32) { sas[threadIdx.x] = a1s[threadIdx.x]; sad[threadIdx.x] = a1d[threadIdx.x]; }
  __syncthreads();
  int n = blockIdx.x * TPB + threadIdx.x;
  if (n >= N) return;
  float w = escore[n] / sumexp[0];
  float f[16];
  {
    float a[8], b[10];
#pragma unroll
    for (int i = 0; i < 8; i++) a[i] = x1[n*8 + i];
#pragma unroll
    for (int i = 0; i < 10; i++) b[i] = x2[n*10 + i];
#pragma unroll
    for (int j = 0; j < 16; j++) {
      float v = sbv[j];
#pragma unroll
      for (int i = 0; i < 8; i++) v += a[i] * sWv[i*16 + j];
#pragma unroll
      for (int i = 0; i < 10; i++) v += b[i] * sWv[(8 + i)*16 + j];
      f[j] = w * v;
    }
  }
  float hr[32], esv[8], edv[8];
#pragma unroll
  for (int j = 0; j < 32; j++) {
    float s = 0.f;
#pragma unroll
    for (int i = 0; i < 16; i++) s += f[i] * sW1[i*32 + j];
    hr[j] = s;
  }
#pragma unroll
  for (int hh = 0; hh < 8; hh++) {
    float s = 0.f, d = 0.f;
#pragma unroll
    for (int c = 0; c < 4; c++) { s += hr[hh*4+c]*sas[hh*4+c]; d += hr[hh*4+c]*sad[hh*4+c]; }
    esv[hh] = s; edv[hh] = d;
  }
  unsigned* ra = rec1a + (size_t)n*10;
  unsigned* rb = rec1b + (size_t)n*10;
  ra[0] = pk(esv[0], esv[1]); ra[1] = pk(esv[2], esv[3]);
  rb[0] = pk(esv[4], esv[5]); rb[1] = pk(esv[6], esv[7]);
#pragma unroll
  for (int hh = 0; hh < 4; hh++) {
    ra[2+2*hh] = pk(hr[hh*4+0], hr[hh*4+1]);
    ra[3+2*hh] = pk(hr[hh*4+2], hr[hh*4+3]);
    rb[2+2*hh] = pk(hr[16+hh*4+0], hr[16+hh*4+1]);
    rb[3+2*hh] = pk(hr[16+hh*4+2], hr[16+hh*4+3]);
  }
  f32x4 e0 = {edv[0], edv[1], edv[2], edv[3]};
  f32x4 e1 = {edv[4], edv[5], edv[6], edv[7]};
  *(f32x4*)(ed + n*8)     = e0;
  *(f32x4*)(ed + n*8 + 4) = e1;
}

__global__ void __launch_bounds__(TPB) k_B2(
    const float* __restrict__ W2, const float* __restrict__ a2s, const float* __restrict__ a2d,
    const float* __restrict__ X,
    unsigned* __restrict__ rec2, float* __restrict__ ed, int N)
{
  __shared__ float sW[512], sas[16], sad[16];
  for (int i = threadIdx.x; i < 512; i += TPB) sW[i] = W2[i];
  if (threadIdx.x < 16) { sas[threadIdx.x] = a2s[threadIdx.x]; sad[threadIdx.x] = a2d[threadIdx.x]; }
  __syncthreads();
  int n = blockIdx.x * TPB + threadIdx.x;
  if (n >= N) return;
  float Xr[32];
#pragma unroll
  for (int i = 0; i < 8; i++) {
    f32x4 t = __builtin_nontemporal_load((const f32x4*)(X + n*32) + i);
    Xr[i*4+0] = t.x; Xr[i*4+1] = t.y; Xr[i*4+2] = t.z; Xr[i*4+3] = t.w;
  }
  float hr[16];
#pragma unroll
  for (int j = 0; j < 16; j++) {
    float s = 0.f;
#pragma unroll
    for (int f = 0; f < 32; f++) s += Xr[f] * sW[f*16 + j];
    hr[j] = s;
  }
  float esv[4], edv[4];
#pragma unroll
  for (int hh = 0; hh < 4; hh++) {
    float s = 0.f, d = 0.f;
#pragma unroll
    for (int c = 0; c < 4; c++) { s += hr[hh*4+c]*sas[hh*4+c]; d += hr[hh*4+c]*sad[hh*4+c]; }
    esv[hh] = s; edv[hh] = d;
  }
  unsigned* r = rec2 + (size_t)n*10;
  r[0] = pk(esv[0], esv[1]); r[1] = pk(esv[2], esv[3]);
#pragma unroll
  for (int hh = 0; hh < 4; hh++) {
    r[2+2*hh] = pk(hr[hh*4+0], hr[hh*4+1]);
    r[3+2*hh] = pk(hr[hh*4+2], hr[hh*4+3]);
  }
  f32x4 e0 = {edv[0], edv[1], edv[2], edv[3]};
  *(f32x4*)(ed + n*8) = e0;
}

__global__ void __launch_bounds__(TPB) k_B3(
    const float* __restrict__ W3, const float* __restrict__ a3s, const float* __restrict__ a3d,
    const float* __restrict__ X3,
    float* __restrict__ rec3, float* __restrict__ ed, int N)
{
  __shared__ float sW[128], sas[8], sad[8];
  for (int i = threadIdx.x; i < 128; i += TPB) sW[i] = W3[i];
  if (threadIdx.x < 8) { sas[threadIdx.x] = a3s[threadIdx.x]; sad[threadIdx.x] = a3d[threadIdx.x]; }
  __syncthreads();
  int n = blockIdx.x * TPB + threadIdx.x;
  if (n >= N) return;
  float Xr[16];
#pragma unroll
  for (int i = 0; i < 4; i++) {
    f32x4 t = __builtin_nontemporal_load((const f32x4*)(X3 + n*16) + i);
    Xr[i*4+0] = t.x; Xr[i*4+1] = t.y; Xr[i*4+2] = t.z; Xr[i*4+3] = t.w;
  }
  float hr[8];
#pragma unroll
  for (int j = 0; j < 8; j++) {
    float s = 0.f;
#pragma unroll
    for (int f = 0; f < 16; f++) s += Xr[f] * sW[f*8 + j];
    hr[j] = s;
  }
  float* r = rec3 + (size_t)n*10;
#pragma unroll
  for (int hh = 0; hh < 2; hh++) {
    float s = 0.f, d = 0.f;
#pragma unroll
    for (int c = 0; c < 4; c++) { s += hr[hh*4+c]*sas[hh*4+c]; d += hr[hh*4+c]*sad[hh*4+c]; }
    r[hh] = s;
    ed[n*8 + hh] = d;
  }
#pragma unroll
  for (int hh = 0; hh < 2; hh++) {
    f32x2 a = {hr[hh*4+0], hr[hh*4+1]};
    f32x2 b = {hr[hh*4+2], hr[hh*4+3]};
    *(f32x2*)(r + 2 + hh*4)     = a;
    *(f32x2*)(r + 2 + hh*4 + 2) = b;
  }
}

// ==================== wave-per-row gather passes ============================
// One 64-lane wave per dst row. Lanes = 4 heads x 16 edge slots; each lane
// handles ~(deg+1)/16 edges incl. the self-loop (t==deg); butterfly-reduce
// z/acc over slots; lanes j==0 write. bf16 records, 40B, L2-resident.
template<int OS, int HOFF>
__global__ void __launch_bounds__(TPB) k_gat4(
    const int* __restrict__ rowptr, const int* __restrict__ rowend, const int* __restrict__ col,
    const unsigned* __restrict__ rec, const float* __restrict__ ed,
    const float* __restrict__ bias, float* __restrict__ out, int N)
{
  int wave = (blockIdx.x * TPB + threadIdx.x) >> 6;
  if (wave >= N) return;
  int lane = threadIdx.x & 63;
  int hh = lane & 3, j = lane >> 2;
  int d = wave;
  int e0 = rowptr[d], deg = rowend[d] - e0;
  float edv = ed[d*8 + HOFF + hh];
  float z = 0.f;
  f32x4 acc = {0.f, 0.f, 0.f, 0.f};
  for (int t = j; t <= deg; t += 16) {
    int s = (t == deg) ? d : __builtin_nontemporal_load(col + e0 + t);
    const unsigned* rp = rec + (size_t)s*10;
    unsigned ew = rp[hh >> 1];
    uint2 hv = *(const uint2*)(rp + 2 + 2*hh);
    float esv = ubf((ew >> ((hh & 1) * 16)) & 0xFFFFu);
    float w = __expf(lrelu(esv + edv));
    z += w;
    acc.x += w * ubf(hv.x & 0xFFFFu); acc.y += w * ubf(hv.x >> 16);
    acc.z += w * ubf(hv.y & 0xFFFFu); acc.w += w * ubf(hv.y >> 16);
  }
#pragma unroll
  for (int m = 4; m < 64; m <<= 1) {
    z += __shfl_xor(z, m);
    acc.x += __shfl_xor(acc.x, m); acc.y += __shfl_xor(acc.y, m);
    acc.z += __shfl_xor(acc.z, m); acc.w += __shfl_xor(acc.w, m);
  }
  if (j == 0) {
    float inv = 1.f / z;
    const f32x4 bb = *(const f32x4*)(bias + (HOFF + hh)*4);
    f32x4 o = { acc.x*inv + bb.x, acc.y*inv + bb.y, acc.z*inv + bb.z, acc.w*inv + bb.w };
    __builtin_nontemporal_store(o, (f32x4*)(out + (size_t)d*OS + (HOFF + hh)*4));
  }
}

// Layer 3 (H=2, fp32 rec3). Lanes = 2 heads x 32 slots.
__global__ void __launch_bounds__(TPB) k_gat3(
    const int* __restrict__ rowptr, const int* __restrict__ rowend, const int* __restrict__ col,
    const float* __restrict__ rec, const float* __restrict__ ed,
    const float* __restrict__ b3, float* __restrict__ x4, int N)
{
  int wave = (blockIdx.x * TPB + threadIdx.x) >> 6;
  if (wave >= N) return;
  int lane = threadIdx.x & 63;
  int hh = lane & 1, j = lane >> 1;
  int d = wave;
  int e0 = rowptr[d], deg = rowend[d] - e0;
  float edv = ed[d*8 + hh];
  float z = 0.f;
  f32x4 acc = {0.f, 0.f, 0.f, 0.f};
  for (int t = j; t <= deg; t += 32) {
    int s = (t == deg) ? d : __builtin_nontemporal_load(col + e0 + t);
    const float* rp = rec + (size_t)s*10;
    float esv = rp[hh];
    f32x2 a = *(const f32x2*)(rp + 2 + hh*4);
    f32x2 b = *(const f32x2*)(rp + 2 + hh*4 + 2);
    float w = __expf(lrelu(esv + edv));
    z += w; acc.x += w*a.x; acc.y += w*a.y; acc.z += w*b.x; acc.w += w*b.y;
  }
#pragma unroll
  for (int m = 2; m < 64; m <<= 1) {
    z += __shfl_xor(z, m);
    acc.x += __shfl_xor(acc.x, m); acc.y += __shfl_xor(acc.y, m);
    acc.z += __shfl_xor(acc.z, m); acc.w += __shfl_xor(acc.w, m);
  }
  if (j == 0) {
    float inv = 1.f / z;
    const f32x4 bb = *(const f32x4*)(b3 + hh*4);
    f32x4 o = { acc.x*inv + bb.x, acc.y*inv + bb.y, acc.z*inv + bb.z, acc.w*inv + bb.w };
    __builtin_nontemporal_store(o, (f32x4*)(x4 + d*8 + hh*4));
  }
}

// Adjacency + final. Lanes = 2 half-vectors x 32 slots (src-CSR rows [N,2N)).
__global__ void __launch_bounds__(TPB) k_adj_final(
    const int* __restrict__ rowptr, const int* __restrict__ rowend, const int* __restrict__ col,
    const float* __restrict__ x4, const float* __restrict__ Wl2,
    float* __restrict__ out, int N)
{
  __shared__ float sW[8];
  if (threadIdx.x < 8) sW[threadIdx.x] = Wl2[threadIdx.x];
  __syncthreads();
  int wave = (blockIdx.x * TPB + threadIdx.x) >> 6;
  if (wave >= N) return;
  int lane = threadIdx.x & 63;
  int q = lane & 1, j = lane >> 1;
  int r = wave;
  int e0 = rowptr[N + r], deg = rowend[N + r] - e0;
  f32x4 acc = {0.f, 0.f, 0.f, 0.f};
  for (int t = j; t < deg; t += 32) {
    int c = __builtin_nontemporal_load(col + e0 + t);
    f32x4 xv = *(const f32x4*)(x4 + c*8 + q*4);
    acc.x += xv.x; acc.y += xv.y; acc.z += xv.z; acc.w += xv.w;
  }
#pragma unroll
  for (int m = 2; m < 64; m <<= 1) {
    acc.x += __shfl_xor(acc.x, m); acc.y += __shfl_xor(acc.y, m);
    acc.z += __shfl_xor(acc.z, m); acc.w += __shfl_xor(acc.w, m);
  }
  float part = 0.f;
  if (j == 0) {
    float inv = deg > 0 ? 1.f / (float)deg : 0.f;
    f32x4 R = { acc.x*inv, acc.y*inv, acc.z*inv, acc.w*inv };
    f32x4 xo = *(const f32x4*)(x4 + r*8 + q*4);
    part = xo.x*R.x + xo.y*R.y + xo.z*R.z + xo.w*R.w
         + R.x*sW[q*4+0] + R.y*sW[q*4+1] + R.z*sW[q*4+2] + R.w*sW[q*4+3];
  }
  part += __shfl_xor(part, 1);
  if (lane == 0) out[r] = part;
}

// ============================ launch ========================================
extern "C" void kernel_launch(void* const* d_in, const int* in_sizes, int n_in,
                              void* d_out, int out_size, void* d_ws, size_t ws_size,
                              hipStream_t stream)
{
  const float* x1  = (const float*)d_in[0];
  const float* x2  = (const float*)d_in[1];
  const int*   ei  = (const int*)d_in[2];
  const float* Wq  = (const float*)d_in[4];
  const float* bq  = (const float*)d_in[5];
  const float* Wk  = (const float*)d_in[6];
  const float* bk  = (const float*)d_in[7];
  const float* Wv  = (const float*)d_in[8];
  const float* bv  = (const float*)d_in[9];
  const float* W1  = (const float*)d_in[10];
  const float* a1s = (const float*)d_in[11];
  const float* a1d = (const float*)d_in[12];
  const float* b1  = (const float*)d_in[13];
  const float* W2  = (const float*)d_in[14];
  const float* a2s = (const float*)d_in[15];
  const float* a2d = (const float*)d_in[16];
  const float* b2  = (const float*)d_in[17];
  const float* W3  = (const float*)d_in[18];
  const float* a3s = (const float*)d_in[19];
  const float* a3d = (const float*)d_in[20];
  const float* b3  = (const float*)d_in[21];
  const float* Wl2 = (const float*)d_in[22];

  int N = in_sizes[0] / 8;
  int E = in_sizes[2] / 2;
  int n2 = 2 * N;
  int NB = (n2 + 255) >> 8;

  // ---- workspace (element offsets all multiples of 4 -> 16B aligned) ----
  int* cursor   = (int*)d_ws;                           // 1024 (zeroed)
  float* sumexp = (float*)(cursor + 1024);              // 16 (1 used, zeroed)
  int* rowptr   = (int*)(sumexp + 16);                  // 2N
  int* rowend   = rowptr + (size_t)n2;                  // 2N
  unsigned* items = (unsigned*)(rowend + (size_t)n2);   // NB*CAP (-> col in place)
  unsigned* rec1a = items + (size_t)NB * CAP;           // 10N (4.0 MB)
  unsigned* rec1b = rec1a + 10ull*N;                    // 10N (later aliased by x4)
  unsigned* rec2  = rec1b + 10ull*N;                    // 10N
  float* rec3     = (float*)(rec2 + 10ull*N);           // 10N
  float* ed       = rec3 + 10ull*N;                     // 8N
  float* escore   = ed + 8ull*N;                        // N
  float* X        = escore + (size_t)N;                 // 32N (X3 aliases, stride 16)
  float* X3 = X;
  float* x4 = (float*)rec1b;                            // 8N (rec1b dead by then)

  int gN  = (N + TPB - 1) / TPB;
  int gB  = (E + EPB - 1) / EPB;
  int g64 = (int)(((long long)N * 64 + TPB - 1) / TPB);  // wave-per-row grids

  (void)hipMemsetAsync(d_ws, 0, (1024 + 16) * sizeof(int), stream);  // cursor + sumexp

  // CSR build
  k_bucket<<<gB, TPB, 0, stream>>>(ei, E, N, cursor, items);
  k_csr<<<NB, TPB, 0, stream>>>(cursor, items, rowptr, rowend, n2);
  int* colv = (int*)items;

  // dense prologue
  k_score<<<gN, TPB, 0, stream>>>(x1, x2, Wq, bq, Wk, bk, escore, sumexp, N);
  k_A1<<<gN, TPB, 0, stream>>>(x1, x2, Wv, bv, W1, a1s, a1d, escore, sumexp, rec1a, rec1b, ed, N);

  // GAT layer 1 (two 4-head passes)
  k_gat4<32, 0><<<g64, TPB, 0, stream>>>(rowptr, rowend, colv, rec1a, ed, b1, X, N);
  k_gat4<32, 4><<<g64, TPB, 0, stream>>>(rowptr, rowend, colv, rec1b, ed, b1, X, N);
  // GAT layer 2
  k_B2<<<gN, TPB, 0, stream>>>(W2, a2s, a2d, X, rec2, ed, N);
  k_gat4<16, 0><<<g64, TPB, 0, stream>>>(rowptr, rowend, colv, rec2, ed, b2, X3, N);
  // GAT layer 3
  k_B3<<<gN, TPB, 0, stream>>>(W3, a3s, a3d, X3, rec3, ed, N);
  k_gat3<<<g64, TPB, 0, stream>>>(rowptr, rowend, colv, rec3, ed, b3, x4, N);

  // adjacency readout
  k_adj_final<<<g64, TPB, 0, stream>>>(rowptr, rowend, colv, x4, Wl2, (float*)d_out, N);
}

// Round 7
// 561.738 us; speedup vs baseline: 1.2940x; 1.0070x over previous
//
#include <hip/hip_runtime.h>

#define TPB 256
#define NBMAX 1024     // max coarse buckets (2N/256 = 782 for N=100000)
#define CAP 9216       // per-bucket capacity (mean 8184, sigma ~90 -> +11 sigma)
#define EPB 2048       // edges per block in k_bucket (8/thread)

typedef float f32x4 __attribute__((ext_vector_type(4)));
typedef float f32x2 __attribute__((ext_vector_type(2)));

__device__ __forceinline__ float lrelu(float x) { return x > 0.f ? x : 0.2f * x; }

// bf16 helpers (RNE pack)
__device__ __forceinline__ unsigned bfr(float x) {
  unsigned u = __float_as_uint(x);
  return (u + 0x7FFFu + ((u >> 16) & 1u)) >> 16;
}
__device__ __forceinline__ unsigned pk(float a, float b) { return bfr(a) | (bfr(b) << 16); }
__device__ __forceinline__ float ubf(unsigned us) { return __uint_as_float(us << 16); }

// ============================ bucketed CSR build ============================
// Pass 1: per-block LDS histogram + scan + bucket-major LDS staging (payload
// AND bucket-id), then ordered coalesced write-out. No dependent LDS chains.
__global__ void __launch_bounds__(TPB) k_bucket(
    const int* __restrict__ ei, int E, int N,
    int* __restrict__ cursor, unsigned* __restrict__ items)
{
  __shared__ int hist[NBMAX];            // counts -> rank counters
  __shared__ int lofs[NBMAX];            // exclusive scan (stage offsets)
  __shared__ int basem[NBMAX];           // b*CAP + resv - lofs[b]
  __shared__ int scan_s[TPB];
  __shared__ unsigned stage[2 * EPB];    // payload, bucket-major
  __shared__ unsigned short bid[2 * EPB];// bucket id per staged item
  int tid = threadIdx.x;
  for (int i = tid; i < NBMAX; i += TPB) hist[i] = 0;
  int s0 = blockIdx.x * EPB;
  int nE = min(EPB, E - s0);
  int sv[EPB / TPB], dv[EPB / TPB];
  __syncthreads();
#pragma unroll
  for (int k = 0; k < EPB / (TPB * 4); k++) {
    int li = tid * 4 + k * TPB * 4;
    if (li + 3 < nE) {
      int4 s4 = *(const int4*)(ei + s0 + li);
      int4 d4 = *(const int4*)(ei + E + s0 + li);
      sv[k*4+0] = s4.x; sv[k*4+1] = s4.y; sv[k*4+2] = s4.z; sv[k*4+3] = s4.w;
      dv[k*4+0] = d4.x; dv[k*4+1] = d4.y; dv[k*4+2] = d4.z; dv[k*4+3] = d4.w;
#pragma unroll
      for (int j = 0; j < 4; j++) {
        atomicAdd(&hist[dv[k*4+j] >> 8], 1);
        atomicAdd(&hist[(N + sv[k*4+j]) >> 8], 1);
      }
    } else {
      for (int j = 0; j < 4; j++) {
        if (li + j < nE) {
          sv[k*4+j] = ei[s0 + li + j];
          dv[k*4+j] = ei[E + s0 + li + j];
          atomicAdd(&hist[dv[k*4+j] >> 8], 1);
          atomicAdd(&hist[(N + sv[k*4+j]) >> 8], 1);
        }
      }
    }
  }
  __syncthreads();
  // 1024-bin exclusive scan; thread t owns bins 4t..4t+3
  int b0 = tid * 4;
  int c0 = hist[b0], c1 = hist[b0 + 1], c2 = hist[b0 + 2], c3 = hist[b0 + 3];
  int tsum = c0 + c1 + c2 + c3;
  scan_s[tid] = tsum;
  __syncthreads();
#pragma unroll
  for (int o = 1; o < TPB; o <<= 1) {
    int t = (tid >= o) ? scan_s[tid - o] : 0;
    __syncthreads();
    scan_s[tid] += t;
    __syncthreads();
  }
  int run = scan_s[tid] - tsum;
  int cs[4] = {c0, c1, c2, c3};
#pragma unroll
  for (int j = 0; j < 4; j++) {
    int b = b0 + j, c = cs[j];
    lofs[b] = run;
    int resv = c ? atomicAdd(&cursor[b], c) : 0;
    basem[b] = b * CAP + resv - run;
    hist[b] = 0;                     // rank counters for phase 3
    run += c;
  }
  __syncthreads();
  // phase 3: rank-scatter payload + bucket id into LDS (bucket-major)
#pragma unroll
  for (int k = 0; k < EPB / TPB; k++) {
    int li = tid * 4 + (k >> 2) * TPB * 4 + (k & 3);   // matches load indexing
    if (li < nE) {
      int s = sv[k], d = dv[k];
      int b1 = d >> 8;
      int p1 = lofs[b1] + atomicAdd(&hist[b1], 1);
      stage[p1] = ((unsigned)(d & 255) << 24) | (unsigned)s;
      bid[p1] = (unsigned short)b1;
      int k2 = N + s, b2 = k2 >> 8;
      int p2 = lofs[b2] + atomicAdd(&hist[b2], 1);
      stage[p2] = ((unsigned)(k2 & 255) << 24) | (unsigned)d;
      bid[p2] = (unsigned short)b2;
    }
  }
  __syncthreads();
  // phase 4: ordered write-out — two independent LDS reads, coalesced runs
  int total = 2 * nE;
  for (int idx = tid; idx < total; idx += TPB) {
    unsigned u = stage[idx];
    int b = bid[idx];
    int dest = basem[b] + idx;
    if (dest < (b + 1) * CAP) items[dest] = u;
  }
}

// Pass 2: one block per bucket — LDS stage (uint4), 256-bin count+scan, scatter
__global__ void __launch_bounds__(TPB) k_csr(
    const int* __restrict__ cursor, unsigned* __restrict__ items,
    int* __restrict__ rowptr, int* __restrict__ rowend, int n2)
{
  __shared__ unsigned stage[CAP];
  __shared__ int cnt_s[TPB], scan_s[TPB], off_s[TPB];
  int tid = threadIdx.x, b = blockIdx.x;
  size_t bbase = (size_t)b * CAP;
  int cnt = min(cursor[b], CAP);
  int c4 = cnt & ~3;
  for (int i = tid * 4; i < c4; i += TPB * 4) {
    uint4 v = *(const uint4*)(items + bbase + i);
    stage[i] = v.x; stage[i+1] = v.y; stage[i+2] = v.z; stage[i+3] = v.w;
  }
  for (int i = c4 + tid; i < cnt; i += TPB) stage[i] = items[bbase + i];
  cnt_s[tid] = 0;
  __syncthreads();
  for (int i = tid; i < cnt; i += TPB) atomicAdd(&cnt_s[stage[i] >> 24], 1);
  __syncthreads();
  int v = cnt_s[tid];
  scan_s[tid] = v;
  __syncthreads();
#pragma unroll
  for (int o = 1; o < TPB; o <<= 1) {
    int t = (tid >= o) ? scan_s[tid - o] : 0;
    __syncthreads();
    scan_s[tid] += t;
    __syncthreads();
  }
  int excl = scan_s[tid] - v;
  off_s[tid] = excl;
  int g = b * 256 + tid;
  if (g < n2) { rowptr[g] = (int)bbase + excl; rowend[g] = (int)bbase + excl + v; }
  cnt_s[tid] = 0;
  __syncthreads();
  for (int i = tid; i < cnt; i += TPB) {
    unsigned u = stage[i];
    int k = u >> 24;
    int r = atomicAdd(&cnt_s[k], 1);
    items[bbase + off_s[k] + r] = u & 0xFFFFFFu;
  }
}

// ============================ dense node kernels ============================

__global__ void __launch_bounds__(TPB) k_score(
    const float* __restrict__ x1, const float* __restrict__ x2,
    const float* __restrict__ Wq, const float* __restrict__ bq,
    const float* __restrict__ Wk, const float* __restrict__ bk,
    float* __restrict__ escore, float* __restrict__ sumexp, int N)
{
  __shared__ float sWq[128], sWk[160], sbq[16], sbk[16];
  for (int i = threadIdx.x; i < 128; i += TPB) sWq[i] = Wq[i];
  for (int i = threadIdx.x; i < 160; i += TPB) sWk[i] = Wk[i];
  if (threadIdx.x < 16) { sbq[threadIdx.x] = bq[threadIdx.x]; sbk[threadIdx.x] = bk[threadIdx.x]; }
  __syncthreads();
  int n = blockIdx.x * TPB + threadIdx.x;
  float e = 0.f;
  if (n < N) {
    float a[8], b[10];
#pragma unroll
    for (int i = 0; i < 8; i++) a[i] = x1[n*8 + i];
#pragma unroll
    for (int i = 0; i < 10; i++) b[i] = x2[n*10 + i];
    float score = 0.f;
#pragma unroll
    for (int j = 0; j < 16; j++) {
      float q = sbq[j], k = sbk[j];
#pragma unroll
      for (int i = 0; i < 8; i++) q += a[i] * sWq[i*16 + j];
#pragma unroll
      for (int i = 0; i < 10; i++) k += b[i] * sWk[i*16 + j];
      score += q * k;
    }
    e = __expf(score);   // |score| small: exp safe without max-subtraction
    escore[n] = e;
  }
  float v = e;
#pragma unroll
  for (int off = 32; off > 0; off >>= 1) v += __shfl_down(v, off);
  __shared__ float red[TPB / 64];
  if ((threadIdx.x & 63) == 0) red[threadIdx.x >> 6] = v;
  __syncthreads();
  if (threadIdx.x == 0) {
    float s = 0.f;
#pragma unroll
    for (int w = 0; w < TPB / 64; w++) s += red[w];
    atomicAdd(sumexp, s);
  }
}

__global__ void __launch_bounds__(TPB) k_A1(
    const float* __restrict__ x1, const float* __restrict__ x2,
    const float* __restrict__ Wv, const float* __restrict__ bv,
    const float* __restrict__ W1, const float* __restrict__ a1s, const float* __restrict__ a1d,
    const float* __restrict__ escore, const float* __restrict__ sumexp,
    unsigned* __restrict__ rec1a, unsigned* __restrict__ rec1b,
    float* __restrict__ ed, int N)
{
  __shared__ float sWv[288], sbv[16], sW1[512], sas[32], sad[32];
  for (int i = threadIdx.x; i < 288; i += TPB) sWv[i] = Wv[i];
  for (int i = threadIdx.x; i < 512; i += TPB) sW1[i] = W1[i];
  if (threadIdx.x < 16) sbv[threadIdx.x] = bv[threadIdx.x];
  if (threadIdx.x < 32) { sas[threadIdx.x] = a1s[threadIdx.x]; sad[threadIdx.x] = a1d[threadIdx.x]; }
  __syncthreads();
  int n = blockIdx.x * TPB + threadIdx.x;
  if (n >= N) return;
  float w = escore[n] / sumexp[0];
  float f[16];
  {
    float a[8], b[10];
#pragma unroll
    for (int i = 0; i < 8; i++) a[i] = x1[n*8 + i];
#pragma unroll
    for (int i = 0; i < 10; i++) b[i] = x2[n*10 + i];
#pragma unroll
    for (int j = 0; j < 16; j++) {
      float v = sbv[j];
#pragma unroll
      for (int i = 0; i < 8; i++) v += a[i] * sWv[i*16 + j];
#pragma unroll
      for (int i = 0; i < 10; i++) v += b[i] * sWv[(8 + i)*16 + j];
      f[j] = w * v;
    }
  }
  float hr[32], esv[8], edv[8];
#pragma unroll
  for (int j = 0; j < 32; j++) {
    float s = 0.f;
#pragma unroll
    for (int i = 0; i < 16; i++) s += f[i] * sW1[i*32 + j];
    hr[j] = s;
  }
#pragma unroll
  for (int hh = 0; hh < 8; hh++) {
    float s = 0.f, d = 0.f;
#pragma unroll
    for (int c = 0; c < 4; c++) { s += hr[hh*4+c]*sas[hh*4+c]; d += hr[hh*4+c]*sad[hh*4+c]; }
    esv[hh] = s; edv[hh] = d;
  }
  unsigned* ra = rec1a + (size_t)n*10;
  unsigned* rb = rec1b + (size_t)n*10;
  ra[0] = pk(esv[0], esv[1]); ra[1] = pk(esv[2], esv[3]);
  rb[0] = pk(esv[4], esv[5]); rb[1] = pk(esv[6], esv[7]);
#pragma unroll
  for (int hh = 0; hh < 4; hh++) {
    ra[2+2*hh] = pk(hr[hh*4+0], hr[hh*4+1]);
    ra[3+2*hh] = pk(hr[hh*4+2], hr[hh*4+3]);
    rb[2+2*hh] = pk(hr[16+hh*4+0], hr[16+hh*4+1]);
    rb[3+2*hh] = pk(hr[16+hh*4+2], hr[16+hh*4+3]);
  }
  f32x4 e0 = {edv[0], edv[1], edv[2], edv[3]};
  f32x4 e1 = {edv[4], edv[5], edv[6], edv[7]};
  *(f32x4*)(ed + n*8)     = e0;
  *(f32x4*)(ed + n*8 + 4) = e1;
}

__global__ void __launch_bounds__(TPB) k_B2(
    const float* __restrict__ W2, const float* __restrict__ a2s, const float* __restrict__ a2d,
    const float* __restrict__ X,
    unsigned* __restrict__ rec2, float* __restrict__ ed, int N)
{
  __shared__ float sW[512], sas[16], sad[16];
  for (int i = threadIdx.x; i < 512; i += TPB) sW[i] = W2[i];
  if (threadIdx.x < 16) { sas[threadIdx.x] = a2s[threadIdx.x]; sad[threadIdx.x] = a2d[threadIdx.x]; }
  __syncthreads();
  int n = blockIdx.x * TPB + threadIdx.x;
  if (n >= N) return;
  float Xr[32];
#pragma unroll
  for (int i = 0; i < 8; i++) {
    f32x4 t = __builtin_nontemporal_load((const f32x4*)(X + n*32) + i);
    Xr[i*4+0] = t.x; Xr[i*4+1] = t.y; Xr[i*4+2] = t.z; Xr[i*4+3] = t.w;
  }
  float hr[16];
#pragma unroll
  for (int j = 0; j < 16; j++) {
    float s = 0.f;
#pragma unroll
    for (int f = 0; f < 32; f++) s += Xr[f] * sW[f*16 + j];
    hr[j] = s;
  }
  float esv[4], edv[4];
#pragma unroll
  for (int hh = 0; hh < 4; hh++) {
    float s = 0.f, d = 0.f;
#pragma unroll
    for (int c = 0; c < 4; c++) { s += hr[hh*4+c]*sas[hh*4+c]; d += hr[hh*4+c]*sad[hh*4+c]; }
    esv[hh] = s; edv[hh] = d;
  }
  unsigned* r = rec2 + (size_t)n*10;
  r[0] = pk(esv[0], esv[1]); r[1] = pk(esv[2], esv[3]);
#pragma unroll
  for (int hh = 0; hh < 4; hh++) {
    r[2+2*hh] = pk(hr[hh*4+0], hr[hh*4+1]);
    r[3+2*hh] = pk(hr[hh*4+2], hr[hh*4+3]);
  }
  f32x4 e0 = {edv[0], edv[1], edv[2], edv[3]};
  *(f32x4*)(ed + n*8) = e0;
}

__global__ void __launch_bounds__(TPB) k_B3(
    const float* __restrict__ W3, const float* __restrict__ a3s, const float* __restrict__ a3d,
    const float* __restrict__ X3,
    float* __restrict__ rec3, float* __restrict__ ed, int N)
{
  __shared__ float sW[128], sas[8], sad[8];
  for (int i = threadIdx.x; i < 128; i += TPB) sW[i] = W3[i];
  if (threadIdx.x < 8) { sas[threadIdx.x] = a3s[threadIdx.x]; sad[threadIdx.x] = a3d[threadIdx.x]; }
  __syncthreads();
  int n = blockIdx.x * TPB + threadIdx.x;
  if (n >= N) return;
  float Xr[16];
#pragma unroll
  for (int i = 0; i < 4; i++) {
    f32x4 t = __builtin_nontemporal_load((const f32x4*)(X3 + n*16) + i);
    Xr[i*4+0] = t.x; Xr[i*4+1] = t.y; Xr[i*4+2] = t.z; Xr[i*4+3] = t.w;
  }
  float hr[8];
#pragma unroll
  for (int j = 0; j < 8; j++) {
    float s = 0.f;
#pragma unroll
    for (int f = 0; f < 16; f++) s += Xr[f] * sW[f*8 + j];
    hr[j] = s;
  }
  float* r = rec3 + (size_t)n*10;
#pragma unroll
  for (int hh = 0; hh < 2; hh++) {
    float s = 0.f, d = 0.f;
#pragma unroll
    for (int c = 0; c < 4; c++) { s += hr[hh*4+c]*sas[hh*4+c]; d += hr[hh*4+c]*sad[hh*4+c]; }
    r[hh] = s;
    ed[n*8 + hh] = d;
  }
#pragma unroll
  for (int hh = 0; hh < 2; hh++) {
    f32x2 a = {hr[hh*4+0], hr[hh*4+1]};
    f32x2 b = {hr[hh*4+2], hr[hh*4+3]};
    *(f32x2*)(r + 2 + hh*4)     = a;
    *(f32x2*)(r + 2 + hh*4 + 2) = b;
  }
}

// ==================== wave-per-row gather passes ============================
// One 64-lane wave per dst row. Lanes = 4 heads x 16 edge slots; self-loop at
// t==deg; butterfly-reduce z/acc over slots; lanes j==0 write.
template<int OS, int HOFF>
__global__ void __launch_bounds__(TPB) k_gat4(
    const int* __restrict__ rowptr, const int* __restrict__ rowend, const int* __restrict__ col,
    const unsigned* __restrict__ rec, const float* __restrict__ ed,
    const float* __restrict__ bias, float* __restrict__ out, int N)
{
  int wave = (blockIdx.x * TPB + threadIdx.x) >> 6;
  if (wave >= N) return;
  int lane = threadIdx.x & 63;
  int hh = lane & 3, j = lane >> 2;
  int d = wave;
  int e0 = rowptr[d], deg = rowend[d] - e0;
  float edv = ed[d*8 + HOFF + hh];
  float z = 0.f;
  f32x4 acc = {0.f, 0.f, 0.f, 0.f};
  for (int t = j; t <= deg; t += 16) {
    int s = (t == deg) ? d : __builtin_nontemporal_load(col + e0 + t);
    const unsigned* rp = rec + (size_t)s*10;
    unsigned ew = rp[hh >> 1];
    uint2 hv = *(const uint2*)(rp + 2 + 2*hh);
    float esv = ubf((ew >> ((hh & 1) * 16)) & 0xFFFFu);
    float w = __expf(lrelu(esv + edv));
    z += w;
    acc.x += w * ubf(hv.x & 0xFFFFu); acc.y += w * ubf(hv.x >> 16);
    acc.z += w * ubf(hv.y & 0xFFFFu); acc.w += w * ubf(hv.y >> 16);
  }
#pragma unroll
  for (int m = 4; m < 64; m <<= 1) {
    z += __shfl_xor(z, m);
    acc.x += __shfl_xor(acc.x, m); acc.y += __shfl_xor(acc.y, m);
    acc.z += __shfl_xor(acc.z, m); acc.w += __shfl_xor(acc.w, m);
  }
  if (j == 0) {
    float inv = 1.f / z;
    const f32x4 bb = *(const f32x4*)(bias + (HOFF + hh)*4);
    f32x4 o = { acc.x*inv + bb.x, acc.y*inv + bb.y, acc.z*inv + bb.z, acc.w*inv + bb.w };
    __builtin_nontemporal_store(o, (f32x4*)(out + (size_t)d*OS + (HOFF + hh)*4));
  }
}

// Layer 3 (H=2, fp32 rec3). Lanes = 2 heads x 32 slots.
__global__ void __launch_bounds__(TPB) k_gat3(
    const int* __restrict__ rowptr, const int* __restrict__ rowend, const int* __restrict__ col,
    const float* __restrict__ rec, const float* __restrict__ ed,
    const float* __restrict__ b3, float* __restrict__ x4, int N)
{
  int wave = (blockIdx.x * TPB + threadIdx.x) >> 6;
  if (wave >= N) return;
  int lane = threadIdx.x & 63;
  int hh = lane & 1, j = lane >> 1;
  int d = wave;
  int e0 = rowptr[d], deg = rowend[d] - e0;
  float edv = ed[d*8 + hh];
  float z = 0.f;
  f32x4 acc = {0.f, 0.f, 0.f, 0.f};
  for (int t = j; t <= deg; t += 32) {
    int s = (t == deg) ? d : __builtin_nontemporal_load(col + e0 + t);
    const float* rp = rec + (size_t)s*10;
    float esv = rp[hh];
    f32x2 a = *(const f32x2*)(rp + 2 + hh*4);
    f32x2 b = *(const f32x2*)(rp + 2 + hh*4 + 2);
    float w = __expf(lrelu(esv + edv));
    z += w; acc.x += w*a.x; acc.y += w*a.y; acc.z += w*b.x; acc.w += w*b.y;
  }
#pragma unroll
  for (int m = 2; m < 64; m <<= 1) {
    z += __shfl_xor(z, m);
    acc.x += __shfl_xor(acc.x, m); acc.y += __shfl_xor(acc.y, m);
    acc.z += __shfl_xor(acc.z, m); acc.w += __shfl_xor(acc.w, m);
  }
  if (j == 0) {
    float inv = 1.f / z;
    const f32x4 bb = *(const f32x4*)(b3 + hh*4);
    f32x4 o = { acc.x*inv + bb.x, acc.y*inv + bb.y, acc.z*inv + bb.z, acc.w*inv + bb.w };
    __builtin_nontemporal_store(o, (f32x4*)(x4 + d*8 + hh*4));
  }
}

// Adjacency + final. Lanes = 2 half-vectors x 32 slots (src-CSR rows [N,2N)).
__global__ void __launch_bounds__(TPB) k_adj_final(
    const int* __restrict__ rowptr, const int* __restrict__ rowend, const int* __restrict__ col,
    const float* __restrict__ x4, const float* __restrict__ Wl2,
    float* __restrict__ out, int N)
{
  __shared__ float sW[8];
  if (threadIdx.x < 8) sW[threadIdx.x] = Wl2[threadIdx.x];
  __syncthreads();
  int wave = (blockIdx.x * TPB + threadIdx.x) >> 6;
  if (wave >= N) return;
  int lane = threadIdx.x & 63;
  int q = lane & 1, j = lane >> 1;
  int r = wave;
  int e0 = rowptr[N + r], deg = rowend[N + r] - e0;
  f32x4 acc = {0.f, 0.f, 0.f, 0.f};
  for (int t = j; t < deg; t += 32) {
    int c = __builtin_nontemporal_load(col + e0 + t);
    f32x4 xv = *(const f32x4*)(x4 + c*8 + q*4);
    acc.x += xv.x; acc.y += xv.y; acc.z += xv.z; acc.w += xv.w;
  }
#pragma unroll
  for (int m = 2; m < 64; m <<= 1) {
    acc.x += __shfl_xor(acc.x, m); acc.y += __shfl_xor(acc.y, m);
    acc.z += __shfl_xor(acc.z, m); acc.w += __shfl_xor(acc.w, m);
  }
  float part = 0.f;
  if (j == 0) {
    float inv = deg > 0 ? 1.f / (float)deg : 0.f;
    f32x4 R = { acc.x*inv, acc.y*inv, acc.z*inv, acc.w*inv };
    f32x4 xo = *(const f32x4*)(x4 + r*8 + q*4);
    part = xo.x*R.x + xo.y*R.y + xo.z*R.z + xo.w*R.w
         + R.x*sW[q*4+0] + R.y*sW[q*4+1] + R.z*sW[q*4+2] + R.w*sW[q*4+3];
  }
  part += __shfl_xor(part, 1);
  if (lane == 0) out[r] = part;
}

// ============================ launch ========================================
extern "C" void kernel_launch(void* const* d_in, const int* in_sizes, int n_in,
                              void* d_out, int out_size, void* d_ws, size_t ws_size,
                              hipStream_t stream)
{
  const float* x1  = (const float*)d_in[0];
  const float* x2  = (const float*)d_in[1];
  const int*   ei  = (const int*)d_in[2];
  const float* Wq  = (const float*)d_in[4];
  const float* bq  = (const float*)d_in[5];
  const float* Wk  = (const float*)d_in[6];
  const float* bk  = (const float*)d_in[7];
  const float* Wv  = (const float*)d_in[8];
  const float* bv  = (const float*)d_in[9];
  const float* W1  = (const float*)d_in[10];
  const float* a1s = (const float*)d_in[11];
  const float* a1d = (const float*)d_in[12];
  const float* b1  = (const float*)d_in[13];
  const float* W2  = (const float*)d_in[14];
  const float* a2s = (const float*)d_in[15];
  const float* a2d = (const float*)d_in[16];
  const float* b2  = (const float*)d_in[17];
  const float* W3  = (const float*)d_in[18];
  const float* a3s = (const float*)d_in[19];
  const float* a3d = (const float*)d_in[20];
  const float* b3  = (const float*)d_in[21];
  const float* Wl2 = (const float*)d_in[22];

  int N = in_sizes[0] / 8;
  int E = in_sizes[2] / 2;
  int n2 = 2 * N;
  int NB = (n2 + 255) >> 8;

  // ---- workspace (element offsets all multiples of 4 -> 16B aligned) ----
  int* cursor   = (int*)d_ws;                           // 1024 (zeroed)
  float* sumexp = (float*)(cursor + 1024);              // 16 (1 used, zeroed)
  int* rowptr   = (int*)(sumexp + 16);                  // 2N
  int* rowend   = rowptr + (size_t)n2;                  // 2N
  unsigned* items = (unsigned*)(rowend + (size_t)n2);   // NB*CAP (-> col in place)
  unsigned* rec1a = items + (size_t)NB * CAP;           // 10N (4.0 MB)
  unsigned* rec1b = rec1a + 10ull*N;                    // 10N (later aliased by x4)
  unsigned* rec2  = rec1b + 10ull*N;                    // 10N
  float* rec3     = (float*)(rec2 + 10ull*N);           // 10N
  float* ed       = rec3 + 10ull*N;                     // 8N
  float* escore   = ed + 8ull*N;                        // N
  float* X        = escore + (size_t)N;                 // 32N (X3 aliases, stride 16)
  float* X3 = X;
  float* x4 = (float*)rec1b;                            // 8N (rec1b dead by then)

  int gN  = (N + TPB - 1) / TPB;
  int gB  = (E + EPB - 1) / EPB;
  int g64 = (int)(((long long)N * 64 + TPB - 1) / TPB);  // wave-per-row grids

  (void)hipMemsetAsync(d_ws, 0, (1024 + 16) * sizeof(int), stream);  // cursor + sumexp

  // CSR build
  k_bucket<<<gB, TPB, 0, stream>>>(ei, E, N, cursor, items);
  k_csr<<<NB, TPB, 0, stream>>>(cursor, items, rowptr, rowend, n2);
  int* colv = (int*)items;

  // dense prologue
  k_score<<<gN, TPB, 0, stream>>>(x1, x2, Wq, bq, Wk, bk, escore, sumexp, N);
  k_A1<<<gN, TPB, 0, stream>>>(x1, x2, Wv, bv, W1, a1s, a1d, escore, sumexp, rec1a, rec1b, ed, N);

  // GAT layer 1 (two 4-head passes)
  k_gat4<32, 0><<<g64, TPB, 0, stream>>>(rowptr, rowend, colv, rec1a, ed, b1, X, N);
  k_gat4<32, 4><<<g64, TPB, 0, stream>>>(rowptr, rowend, colv, rec1b, ed, b1, X, N);
  // GAT layer 2
  k_B2<<<gN, TPB, 0, stream>>>(W2, a2s, a2d, X, rec2, ed, N);
  k_gat4<16, 0><<<g64, TPB, 0, stream>>>(rowptr, rowend, colv, rec2, ed, b2, X3, N);
  // GAT layer 3
  k_B3<<<gN, TPB, 0, stream>>>(W3, a3s, a3d, X3, rec3, ed, N);
  k_gat3<<<g64, TPB, 0, stream>>>(rowptr, rowend, colv, rec3, ed, b3, x4, N);

  // adjacency readout
  k_adj_final<<<g64, TPB, 0, stream>>>(rowptr, rowend, colv, x4, Wl2, (float*)d_out, N);
}